// Round 6
// baseline (130.812 us; speedup 1.0000x reference)
//
#include <hip/hip_runtime.h>
#include <hip/hip_bf16.h>
#include <math.h>

#define Bsz 2
#define Lsz 1024
#define Dsz 1024
#define Hsz 16
#define Dh 64
#define Mtot (Bsz*Lsz)   // 2048
#define NC (Lsz/64)      // 16 chunks per (b,h)
#define LPAD 72          // LDS row pitch (bf16): 144B = 9*16B, keeps b128 alignment

typedef __bf16 bf16_t;
typedef bf16_t bf16x8 __attribute__((ext_vector_type(8)));
typedef bf16_t bf16x4 __attribute__((ext_vector_type(4)));
typedef float f32x4v __attribute__((ext_vector_type(4)));

__device__ __forceinline__ void gload16(const void* g, void* l) {
    __builtin_amdgcn_global_load_lds(
        (const __attribute__((address_space(1))) unsigned int*)g,
        (__attribute__((address_space(3))) unsigned int*)l, 16, 0, 0);
}

// ---------------- bf16 MFMA GEMM, 3-deep counted-vmcnt pipeline ----------------
// MODE 0: A(2048x1024) @ Wt[0..3]^T fused (grid.y=32); epilogue writes bf16
//         Q, q2=f(Q), K, V, k2=sigmoid(z*0.02/32) per projection p.
// MODE 1: A=yb @ Wt[4]^T (grid.y=8); epilogue writes f32 out + bias.
template<int MODE>
__global__ __launch_bounds__(256) void bgemm_kernel(
    const bf16_t* __restrict__ A, const bf16_t* __restrict__ Bt,
    const float* b0, const float* b1, const float* b2, const float* b3,
    bf16_t* Qo, bf16_t* q2o, bf16_t* Ko, bf16_t* Vo, bf16_t* k2o, float* Cout)
{
    __shared__ __align__(16) bf16_t As[3][4096];
    __shared__ __align__(16) bf16_t Bs[3][4096];
    const int tid  = threadIdx.x;
    const int lane = tid & 63;
    const int wid  = tid >> 6;
    const int row0  = blockIdx.x * 128;
    const int col0g = blockIdx.y * 128;
    const int p    = col0g >> 10;
    const int col0 = col0g & 1023;
    const int wr = (wid >> 1) * 64;
    const int wc = (wid & 1) * 64;

    // staging: thread t stages 16B chunks t and t+256 per tile (row=c>>2,
    // col16=c&3); source column pre-swizzled (linear LDS dest, rule 21).
    const int srow = tid >> 2;
    const int scol = tid & 3;
    const int ssw  = (srow & 3) ^ ((srow >> 2) & 3);
    const int scol_sw = scol ^ ssw;
    const bf16_t* gA0 = A  + (size_t)(row0 + srow)       * 1024 + scol_sw * 8;
    const bf16_t* gA1 = A  + (size_t)(row0 + srow + 64)  * 1024 + scol_sw * 8;
    const bf16_t* gB0 = Bt + (size_t)(col0g + srow)      * 1024 + scol_sw * 8;
    const bf16_t* gB1 = Bt + (size_t)(col0g + srow + 64) * 1024 + scol_sw * 8;

    const int laneRow = lane & 15;
    const int kblk = lane >> 4;
    const int swz = (kblk ^ (laneRow & 3) ^ ((laneRow >> 2) & 3)) & 3;
    const int aoff = (wr + laneRow) * 32 + swz * 8;
    const int boff = (wc + laneRow) * 32 + swz * 8;

    f32x4v acc[4][4];
    #pragma unroll
    for (int i = 0; i < 4; ++i)
        #pragma unroll
        for (int j = 0; j < 4; ++j)
            acc[i][j] = (f32x4v){0.f, 0.f, 0.f, 0.f};

    auto stage = [&](int buf) {
        gload16(gA0, &As[buf][tid * 8]);
        gload16(gA1, &As[buf][(tid + 256) * 8]);
        gload16(gB0, &Bs[buf][tid * 8]);
        gload16(gB1, &Bs[buf][(tid + 256) * 8]);
        gA0 += 32; gA1 += 32; gB0 += 32; gB1 += 32;
    };

    stage(0); stage(1); stage(2);              // tiles 0,1,2 in flight (12 loads)
    asm volatile("s_waitcnt vmcnt(8)" ::: "memory");   // tile 0 resident
    __builtin_amdgcn_s_barrier();

    int cur = 0;
    for (int t = 0; t < 32; ++t) {
        bf16x8 af[4], bfr[4];
        #pragma unroll
        for (int f = 0; f < 4; ++f) {
            af[f]  = *reinterpret_cast<const bf16x8*>(&As[cur][aoff + f * 512]);
            bfr[f] = *reinterpret_cast<const bf16x8*>(&Bs[cur][boff + f * 512]);
        }
        asm volatile("s_waitcnt lgkmcnt(0)" ::: "memory");  // this wave's reads done
        __builtin_amdgcn_s_barrier();                       // all waves done with buf[cur]
        if (t < 29) stage(cur);                             // tile t+3 -> vacated buffer
        #pragma unroll
        for (int i = 0; i < 4; ++i)
            #pragma unroll
            for (int j = 0; j < 4; ++j)
                acc[i][j] = __builtin_amdgcn_mfma_f32_16x16x32_bf16(af[i], bfr[j], acc[i][j], 0, 0, 0);
        // counted drain: ensure tile t+1 resident; never vmcnt(0) in steady state
        if (t < 29)      { asm volatile("s_waitcnt vmcnt(8)" ::: "memory"); }
        else if (t == 29){ asm volatile("s_waitcnt vmcnt(4)" ::: "memory"); }
        else             { asm volatile("s_waitcnt vmcnt(0)" ::: "memory"); }
        __builtin_amdgcn_s_barrier();
        cur = (cur == 2) ? 0 : cur + 1;
    }

    // epilogue: C/D layout col=lane&15, row=(lane>>4)*4+e
    const int crowb = row0 + wr + kblk * 4;
    const int ccolb = col0 + wc + laneRow;
    const float* bias = (MODE == 1) ? b0 : (p == 0) ? b0 : (p == 1) ? b1 : (p == 2) ? b2 : b3;
    float bv[4];
    #pragma unroll
    for (int j = 0; j < 4; ++j) bv[j] = bias[ccolb + j * 16];
    #pragma unroll
    for (int i = 0; i < 4; ++i)
        #pragma unroll
        for (int j = 0; j < 4; ++j)
            #pragma unroll
            for (int e = 0; e < 4; ++e) {
                const float val = acc[i][j][e] + bv[j];
                const size_t idx = (size_t)(crowb + i * 16 + e) * 1024 + ccolb + j * 16;
                if (MODE == 1) {
                    Cout[idx] = val;
                } else if (p == 0) {
                    Qo[idx]  = (bf16_t)val;
                    q2o[idx] = (bf16_t)((val >= 0.f ? 0.02f * val : val) * 0.125f);
                } else if (p == 1) {
                    Ko[idx] = (bf16_t)val;
                } else if (p == 2) {
                    Vo[idx] = (bf16_t)val;
                } else {
                    k2o[idx] = (bf16_t)(1.f / (1.f + __expf(-val * 0.000625f)));
                }
            }
}

// ---------------- prep: 5x W transpose-cast (z<5) + x cast (z==5) ----------------
__global__ __launch_bounds__(256) void prep_kernel(
    const float* __restrict__ x, bf16_t* __restrict__ xb,
    const float* __restrict__ W0, const float* __restrict__ W1,
    const float* __restrict__ W2, const float* __restrict__ W3,
    const float* __restrict__ W4, bf16_t* __restrict__ Wt)
{
    const int z = blockIdx.z;
    const int tid = threadIdx.x;
    if (z == 5) {
        const int lin = blockIdx.y * 16 + blockIdx.x;   // 0..255
        #pragma unroll
        for (int u = 0; u < 8; ++u) {
            const size_t s = (size_t)lin * 2048 + u * 256 + tid;
            float4 v = *reinterpret_cast<const float4*>(&x[s * 4]);
            bf16x4 o;
            o[0] = (bf16_t)v.x; o[1] = (bf16_t)v.y; o[2] = (bf16_t)v.z; o[3] = (bf16_t)v.w;
            *reinterpret_cast<bf16x4*>(&xb[s * 4]) = o;
        }
        return;
    }
    const float* W = (z == 0) ? W0 : (z == 1) ? W1 : (z == 2) ? W2 : (z == 3) ? W3 : W4;
    bf16_t* T = Wt + (size_t)z * 1048576;

    __shared__ float Ls[64][65];
    const int k0 = blockIdx.x * 64;
    const int n0 = blockIdx.y * 64;
    const int r  = tid >> 4;
    const int c4 = (tid & 15) * 4;
    #pragma unroll
    for (int i = 0; i < 4; ++i) {
        float4 v = *reinterpret_cast<const float4*>(&W[(size_t)(k0 + r + i * 16) * Dsz + n0 + c4]);
        Ls[r + i * 16][c4 + 0] = v.x;
        Ls[r + i * 16][c4 + 1] = v.y;
        Ls[r + i * 16][c4 + 2] = v.z;
        Ls[r + i * 16][c4 + 3] = v.w;
    }
    __syncthreads();
    #pragma unroll
    for (int i = 0; i < 4; ++i) {
        const int n = r + i * 16;
        bf16x4 o;
        o[0] = (bf16_t)Ls[c4 + 0][n];
        o[1] = (bf16_t)Ls[c4 + 1][n];
        o[2] = (bf16_t)Ls[c4 + 2][n];
        o[3] = (bf16_t)Ls[c4 + 3][n];
        *reinterpret_cast<bf16x4*>(&T[(size_t)(n0 + n) * Dsz + k0 + c4]) = o;
    }
}

// ---------------- fused dual-branch chunked scan ----------------
// One block per (b,h); 4 waves; 16 chunks sequential. States S1^T,S2^T persist
// in MFMA accumulators (exclusive chunk prefix for free); bf16 copies in LDS
// feed the Q@S inter matmuls. All intermediates stay on-chip; only yb leaves.
// Transposed-staged tiles (Kt,Vt,k2t) use an XOR col8 swizzle: write addr
// r*LPAD + ((c>>3 ^ (r>>3))<<3) + (c&7) -> conflict-free scatter, ~free reads.
#define TSWZ(r, c0) (((((c0) >> 3) ^ (((r) >> 3) & 7)) << 3))

__global__ __launch_bounds__(256) void fused_scan_kernel(
    const bf16_t* __restrict__ Qr, const bf16_t* __restrict__ q2p,
    const bf16_t* __restrict__ Kp, const bf16_t* __restrict__ Vp,
    const bf16_t* __restrict__ k2p, const float* __restrict__ x,
    bf16_t* __restrict__ yb)
{
    __shared__ __align__(16) bf16_t sQ [64 * LPAD];
    __shared__ __align__(16) bf16_t sK [64 * LPAD];
    __shared__ __align__(16) bf16_t sKt[64 * LPAD];
    __shared__ __align__(16) bf16_t sVt[64 * LPAD];
    __shared__ __align__(16) bf16_t sQ2[64 * LPAD];
    __shared__ __align__(16) bf16_t sK2[64 * LPAD];
    __shared__ __align__(16) bf16_t sk2t[64 * LPAD];
    __shared__ __align__(16) bf16_t sEt[64 * LPAD];
    __shared__ __align__(16) bf16_t sP [64 * LPAD];
    __shared__ __align__(16) bf16_t sS1t[64 * LPAD];
    __shared__ __align__(16) bf16_t sS2t[64 * LPAD];
    __shared__ __align__(16) bf16_t sO1[64 * LPAD];
    __shared__ __align__(16) bf16_t sO2[64 * LPAD];
    __shared__ bf16_t carry[2][64];

    const int bh = blockIdx.x;
    const int b = bh >> 4, h = bh & 15;
    const int tid = threadIdx.x;
    const int wid = tid >> 6;
    const int lane = tid & 63;
    const int lr = lane & 15;
    const int kb = lane >> 4;
    const int m0 = wid * 16;

    // persistent state accumulators: wave owns S^T rows m0..m0+15, all 64 cols
    f32x4v acct1[4], acct2[4];
    #pragma unroll
    for (int n = 0; n < 4; ++n) {
        acct1[n] = (f32x4v){0.f, 0.f, 0.f, 0.f};
        acct2[n] = (f32x4v){0.f, 0.f, 0.f, 0.f};
    }
    for (int idx = tid; idx < 64 * LPAD; idx += 256) {
        sS1t[idx] = (bf16_t)0.f;
        sS2t[idx] = (bf16_t)0.f;
    }
    if (tid < 64) carry[0][tid] = (bf16_t)0.f;

    for (int c = 0; c < NC; ++c) {
        const size_t gbase = ((size_t)b * Lsz + (size_t)c * 64) * Dsz + (size_t)h * Dh;

        // ---- phase 1: stage Q,K,q2,k2 row-major; Kt,Vt,k2t swizzle-transposed;
        //               prefetch x rows for E into regs
        float xr[16];
        #pragma unroll
        for (int n = 0; n < 4; ++n)
            #pragma unroll
            for (int e = 0; e < 4; ++e) {
                const int i = m0 + kb * 4 + e;
                const int col = n * 16 + lr;
                const int lg = c * 64 + i;
                xr[n * 4 + e] = (lg < Lsz - 1) ? x[gbase + (size_t)(i + 1) * 1024 + col] : 0.f;
            }
        #pragma unroll
        for (int it = 0; it < 2; ++it) {
            const int cc = tid + it * 256;
            const int j = cc >> 3;
            const int d0 = (cc & 7) * 8;
            const size_t g = gbase + (size_t)j * 1024 + d0;
            bf16x8 qv  = *reinterpret_cast<const bf16x8*>(&Qr[g]);
            bf16x8 kv  = *reinterpret_cast<const bf16x8*>(&Kp[g]);
            bf16x8 vv  = *reinterpret_cast<const bf16x8*>(&Vp[g]);
            bf16x8 q2v = *reinterpret_cast<const bf16x8*>(&q2p[g]);
            bf16x8 k2v = *reinterpret_cast<const bf16x8*>(&k2p[g]);
            *reinterpret_cast<bf16x8*>(&sQ [j * LPAD + d0]) = qv;
            *reinterpret_cast<bf16x8*>(&sK [j * LPAD + d0]) = kv;
            *reinterpret_cast<bf16x8*>(&sQ2[j * LPAD + d0]) = q2v;
            *reinterpret_cast<bf16x8*>(&sK2[j * LPAD + d0]) = k2v;
            #pragma unroll
            for (int i = 0; i < 8; ++i) {
                const int r = d0 + i;
                const int sw = r * LPAD + TSWZ(r, j) + (j & 7);
                sKt [sw] = kv[i];
                sVt [sw] = vv[i];
                sk2t[sw] = k2v[i];
            }
        }
        __syncthreads();

        // ---- phase 2: P1 = Q.K^T, Ointer1 = Q.S1, S1 += K^T V (acc)
        f32x4v accp[4], acci[4];
        #pragma unroll
        for (int n = 0; n < 4; ++n) { accp[n] = (f32x4v){0,0,0,0}; acci[n] = (f32x4v){0,0,0,0}; }
        #pragma unroll
        for (int kk = 0; kk < 2; ++kk) {
            const int c0 = kk * 32 + kb * 8;
            const int ra = m0 + lr;
            bf16x8 aq = *reinterpret_cast<const bf16x8*>(&sQ [ra * LPAD + c0]);
            bf16x8 av = *reinterpret_cast<const bf16x8*>(&sVt[ra * LPAD + TSWZ(ra, c0)]);
            #pragma unroll
            for (int n = 0; n < 4; ++n) {
                const int rb = n * 16 + lr;
                bf16x8 bk = *reinterpret_cast<const bf16x8*>(&sK  [rb * LPAD + c0]);
                bf16x8 bs = *reinterpret_cast<const bf16x8*>(&sS1t[rb * LPAD + c0]);
                bf16x8 bt = *reinterpret_cast<const bf16x8*>(&sKt [rb * LPAD + TSWZ(rb, c0)]);
                accp[n]  = __builtin_amdgcn_mfma_f32_16x16x32_bf16(aq, bk, accp[n], 0, 0, 0);
                acci[n]  = __builtin_amdgcn_mfma_f32_16x16x32_bf16(aq, bs, acci[n], 0, 0, 0);
                acct1[n] = __builtin_amdgcn_mfma_f32_16x16x32_bf16(av, bt, acct1[n], 0, 0, 0);
            }
        }
        #pragma unroll
        for (int n = 0; n < 4; ++n)
            #pragma unroll
            for (int e = 0; e < 4; ++e) {
                const int i = m0 + kb * 4 + e;
                const int j = n * 16 + lr;
                sP[i * LPAD + j] = (bf16_t)((j <= i) ? accp[n][e] : 0.f);
            }
        __syncthreads();

        // ---- phase 3: Oi1 = P1.V; O1 = Oi1 + Ointer1; E = x[l+1]-O1;
        //               write sO1, sEt, new sS1t
        f32x4v acco[4];
        #pragma unroll
        for (int n = 0; n < 4; ++n) acco[n] = (f32x4v){0,0,0,0};
        #pragma unroll
        for (int kk = 0; kk < 2; ++kk) {
            const int c0 = kk * 32 + kb * 8;
            bf16x8 ap = *reinterpret_cast<const bf16x8*>(&sP[(m0 + lr) * LPAD + c0]);
            #pragma unroll
            for (int n = 0; n < 4; ++n) {
                const int rb = n * 16 + lr;
                bf16x8 bv = *reinterpret_cast<const bf16x8*>(&sVt[rb * LPAD + TSWZ(rb, c0)]);
                acco[n] = __builtin_amdgcn_mfma_f32_16x16x32_bf16(ap, bv, acco[n], 0, 0, 0);
            }
        }
        #pragma unroll
        for (int n = 0; n < 4; ++n)
            #pragma unroll
            for (int e = 0; e < 4; ++e) {
                const int i = m0 + kb * 4 + e;
                const int col = n * 16 + lr;
                const int lg = c * 64 + i;
                const float o1 = acco[n][e] + acci[n][e];
                sO1[i * LPAD + col] = (bf16_t)o1;
                const float ev = (lg < Lsz - 1) ? (xr[n * 4 + e] - o1) : 0.f;
                sEt[col * LPAD + i] = (bf16_t)ev;
                sS1t[i * LPAD + col] = (bf16_t)acct1[n][e];
            }
        __syncthreads();

        // ---- phase 4: P2 = q2.k2^T, Ointer2 = q2.S2, S2 += k2^T E (acc)
        #pragma unroll
        for (int n = 0; n < 4; ++n) { accp[n] = (f32x4v){0,0,0,0}; acci[n] = (f32x4v){0,0,0,0}; }
        #pragma unroll
        for (int kk = 0; kk < 2; ++kk) {
            const int c0 = kk * 32 + kb * 8;
            const int ra = m0 + lr;
            bf16x8 aq = *reinterpret_cast<const bf16x8*>(&sQ2[ra * LPAD + c0]);
            bf16x8 ae = *reinterpret_cast<const bf16x8*>(&sEt[ra * LPAD + c0]);
            #pragma unroll
            for (int n = 0; n < 4; ++n) {
                const int rb = n * 16 + lr;
                bf16x8 bk = *reinterpret_cast<const bf16x8*>(&sK2 [rb * LPAD + c0]);
                bf16x8 bs = *reinterpret_cast<const bf16x8*>(&sS2t[rb * LPAD + c0]);
                bf16x8 bt = *reinterpret_cast<const bf16x8*>(&sk2t[rb * LPAD + TSWZ(rb, c0)]);
                accp[n]  = __builtin_amdgcn_mfma_f32_16x16x32_bf16(aq, bk, accp[n], 0, 0, 0);
                acci[n]  = __builtin_amdgcn_mfma_f32_16x16x32_bf16(aq, bs, acci[n], 0, 0, 0);
                acct2[n] = __builtin_amdgcn_mfma_f32_16x16x32_bf16(ae, bt, acct2[n], 0, 0, 0);
            }
        }
        #pragma unroll
        for (int n = 0; n < 4; ++n)
            #pragma unroll
            for (int e = 0; e < 4; ++e) {
                const int i = m0 + kb * 4 + e;
                const int j = n * 16 + lr;
                sP[i * LPAD + j] = (bf16_t)((j <= i) ? accp[n][e] : 0.f);
            }
        __syncthreads();

        // ---- phase 5: Oi2 = P2.E; O2 = Oi2 + Ointer2; write sO2, new sS2t
        #pragma unroll
        for (int n = 0; n < 4; ++n) acco[n] = (f32x4v){0,0,0,0};
        #pragma unroll
        for (int kk = 0; kk < 2; ++kk) {
            const int c0 = kk * 32 + kb * 8;
            bf16x8 ap = *reinterpret_cast<const bf16x8*>(&sP[(m0 + lr) * LPAD + c0]);
            #pragma unroll
            for (int n = 0; n < 4; ++n) {
                bf16x8 be = *reinterpret_cast<const bf16x8*>(&sEt[(n * 16 + lr) * LPAD + c0]);
                acco[n] = __builtin_amdgcn_mfma_f32_16x16x32_bf16(ap, be, acco[n], 0, 0, 0);
            }
        }
        #pragma unroll
        for (int n = 0; n < 4; ++n)
            #pragma unroll
            for (int e = 0; e < 4; ++e) {
                const int i = m0 + kb * 4 + e;
                const int col = n * 16 + lr;
                sO2[i * LPAD + col] = (bf16_t)(acco[n][e] + acci[n][e]);
                sS2t[i * LPAD + col] = (bf16_t)acct2[n][e];
            }
        __syncthreads();

        // ---- phase 6: y[l] = O1[l] + O2[l-1]; save carry row
        #pragma unroll
        for (int it = 0; it < 2; ++it) {
            const int cc = tid + it * 256;
            const int j = cc >> 3;
            const int d0 = (cc & 7) * 8;
            bf16x8 o1v = *reinterpret_cast<const bf16x8*>(&sO1[j * LPAD + d0]);
            bf16x8 o2v;
            if (j > 0) {
                o2v = *reinterpret_cast<const bf16x8*>(&sO2[(j - 1) * LPAD + d0]);
            } else {
                #pragma unroll
                for (int i = 0; i < 8; ++i) o2v[i] = carry[c & 1][d0 + i];
            }
            bf16x8 yv;
            #pragma unroll
            for (int i = 0; i < 8; ++i)
                yv[i] = (bf16_t)((float)o1v[i] + (float)o2v[i]);
            *reinterpret_cast<bf16x8*>(&yb[gbase + (size_t)j * 1024 + d0]) = yv;
        }
        if (tid < 8) {
            const int d0 = tid * 8;
            #pragma unroll
            for (int i = 0; i < 8; ++i)
                carry[(c + 1) & 1][d0 + i] = sO2[63 * LPAD + d0 + i];
        }
        __syncthreads();
    }
}

extern "C" void kernel_launch(void* const* d_in, const int* in_sizes, int n_in,
                              void* d_out, int out_size, void* d_ws, size_t ws_size,
                              hipStream_t stream) {
    const float* x   = (const float*)d_in[0];
    const float* Wq  = (const float*)d_in[1];
    const float* bq  = (const float*)d_in[2];
    const float* Wk1 = (const float*)d_in[3];
    const float* bk1 = (const float*)d_in[4];
    const float* Wv  = (const float*)d_in[5];
    const float* bv  = (const float*)d_in[6];
    const float* Wk2 = (const float*)d_in[7];
    const float* bk2 = (const float*)d_in[8];
    const float* Wp  = (const float*)d_in[9];
    const float* bp  = (const float*)d_in[10];
    float* out = (float*)d_out;
    float* ws  = (float*)d_ws;

    const size_t M1 = 1048576;   // 1M
    bf16_t* xb = (bf16_t*)ws;                      // 2M bf16 = 1M f32
    bf16_t* Wt = (bf16_t*)(ws + M1);               // 5M bf16 = 2.5M f32
    bf16_t* Qr = (bf16_t*)(ws + 3 * M1 + M1 / 2);  // each 2M bf16 = 1M f32...
    bf16_t* q2 = Qr + 2 * M1;
    bf16_t* Kb = Qr + 4 * M1;
    bf16_t* Vb = Qr + 6 * M1;
    bf16_t* k2 = Qr + 8 * M1;
    bf16_t* yb = Qr + 10 * M1;

    dim3 block(256);

    prep_kernel<<<dim3(16, 16, 6), block, 0, stream>>>(x, xb, Wq, Wk1, Wv, Wk2, Wp, Wt);

    // fused Q/K/V/Z projections with elementwise epilogues
    bgemm_kernel<0><<<dim3(16, 32), block, 0, stream>>>(
        xb, Wt, bq, bk1, bv, bk2, Qr, q2, Kb, Vb, k2, nullptr);

    // both scan branches, one kernel, states resident in accumulators
    fused_scan_kernel<<<dim3(Bsz * Hsz), block, 0, stream>>>(Qr, q2, Kb, Vb, k2, x, yb);

    bgemm_kernel<1><<<dim3(16, 8), block, 0, stream>>>(
        yb, Wt + 4 * M1, bp, nullptr, nullptr, nullptr,
        nullptr, nullptr, nullptr, nullptr, nullptr, out);
}

// Round 7
// 101.690 us; speedup vs baseline: 1.2864x; 1.2864x over previous
//
#include <hip/hip_runtime.h>
#include <hip/hip_bf16.h>
#include <math.h>

#define Bsz 2
#define Lsz 1024
#define Dsz 1024
#define Hsz 16
#define Dh 64
#define Mtot (Bsz*Lsz)   // 2048
#define NC (Lsz/64)      // 16 chunks per (b,h)
#define LPAD 72          // LDS row pitch (bf16): 144B = 9*16B

typedef __bf16 bf16_t;
typedef bf16_t bf16x8 __attribute__((ext_vector_type(8)));
typedef bf16_t bf16x4 __attribute__((ext_vector_type(4)));
typedef float f32x4v __attribute__((ext_vector_type(4)));

__device__ __forceinline__ void gload16(const void* g, void* l) {
    __builtin_amdgcn_global_load_lds(
        (const __attribute__((address_space(1))) unsigned int*)g,
        (__attribute__((address_space(3))) unsigned int*)l, 16, 0, 0);
}

// ---------------- bf16 MFMA GEMM, 3-deep counted-vmcnt pipeline ----------------
// MODE 0: A(2048x1024) @ Wt[0..3]^T fused (512 blocks, 16 rows x 32 colblocks);
//         epilogue writes bf16 Q, q2=f(Q), K, V, k2=sigmoid(z*0.02/32).
// MODE 1: A=yb @ Wt[4]^T (128 blocks, 16 x 8); epilogue writes f32 out + bias.
// 1D grid with XCD-aware mapping: blockIdx.x%8 = XCD (m09 round-robin); each XCD
// owns a square block region so its L2 working set is ~4MB (A panel + B panel).
template<int MODE>
__global__ __launch_bounds__(256) void bgemm_kernel(
    const bf16_t* __restrict__ A, const bf16_t* __restrict__ Bt,
    const float* b0, const float* b1, const float* b2, const float* b3,
    bf16_t* Qo, bf16_t* q2o, bf16_t* Ko, bf16_t* Vo, bf16_t* k2o, float* Cout)
{
    __shared__ __align__(16) bf16_t As[3][4096];
    __shared__ __align__(16) bf16_t Bs[3][4096];
    const int tid  = threadIdx.x;
    const int lane = tid & 63;
    const int wid  = tid >> 6;

    // XCD-aware block mapping
    const int lin = blockIdx.x;
    const int xcd = lin & 7;
    const int t0  = lin >> 3;
    int brow, bcolg;
    if (MODE == 0) {            // 2x4 regions of 8x8 blocks (16 rows x 32 cols)
        brow  = (xcd & 1) * 8 + (t0 & 7);
        bcolg = (xcd >> 1) * 8 + (t0 >> 3);
    } else {                    // 4x2 regions of 4x4 blocks (16 rows x 8 cols)
        brow  = (xcd & 3) * 4 + (t0 & 3);
        bcolg = (xcd >> 2) * 4 + (t0 >> 2);
    }
    const int row0  = brow * 128;
    const int col0g = bcolg * 128;
    const int p    = col0g >> 10;
    const int col0 = col0g & 1023;
    const int wr = (wid >> 1) * 64;
    const int wc = (wid & 1) * 64;

    // staging: thread t stages 16B chunks t and t+256 per tile (row=c>>2,
    // col16=c&3); source column pre-swizzled (linear LDS dest, rule 21).
    const int srow = tid >> 2;
    const int scol = tid & 3;
    const int ssw  = (srow & 3) ^ ((srow >> 2) & 3);
    const int scol_sw = scol ^ ssw;
    const bf16_t* gA0 = A  + (size_t)(row0 + srow)       * 1024 + scol_sw * 8;
    const bf16_t* gA1 = A  + (size_t)(row0 + srow + 64)  * 1024 + scol_sw * 8;
    const bf16_t* gB0 = Bt + (size_t)(col0g + srow)      * 1024 + scol_sw * 8;
    const bf16_t* gB1 = Bt + (size_t)(col0g + srow + 64) * 1024 + scol_sw * 8;

    const int laneRow = lane & 15;
    const int kblk = lane >> 4;
    const int swz = (kblk ^ (laneRow & 3) ^ ((laneRow >> 2) & 3)) & 3;
    const int aoff = (wr + laneRow) * 32 + swz * 8;
    const int boff = (wc + laneRow) * 32 + swz * 8;

    f32x4v acc[4][4];
    #pragma unroll
    for (int i = 0; i < 4; ++i)
        #pragma unroll
        for (int j = 0; j < 4; ++j)
            acc[i][j] = (f32x4v){0.f, 0.f, 0.f, 0.f};

    auto stage = [&](int buf) {
        gload16(gA0, &As[buf][tid * 8]);
        gload16(gA1, &As[buf][(tid + 256) * 8]);
        gload16(gB0, &Bs[buf][tid * 8]);
        gload16(gB1, &Bs[buf][(tid + 256) * 8]);
        gA0 += 32; gA1 += 32; gB0 += 32; gB1 += 32;
    };

    stage(0); stage(1); stage(2);              // tiles 0,1,2 in flight (12 loads)
    asm volatile("s_waitcnt vmcnt(8)" ::: "memory");   // tile 0 resident
    __builtin_amdgcn_s_barrier();

    int cur = 0;
    for (int t = 0; t < 32; ++t) {
        bf16x8 af[4], bfr[4];
        #pragma unroll
        for (int f = 0; f < 4; ++f) {
            af[f]  = *reinterpret_cast<const bf16x8*>(&As[cur][aoff + f * 512]);
            bfr[f] = *reinterpret_cast<const bf16x8*>(&Bs[cur][boff + f * 512]);
        }
        asm volatile("s_waitcnt lgkmcnt(0)" ::: "memory");  // this wave's reads done
        __builtin_amdgcn_s_barrier();                       // all waves done with buf[cur]
        if (t < 29) stage(cur);                             // tile t+3 -> vacated buffer
        #pragma unroll
        for (int i = 0; i < 4; ++i)
            #pragma unroll
            for (int j = 0; j < 4; ++j)
                acc[i][j] = __builtin_amdgcn_mfma_f32_16x16x32_bf16(af[i], bfr[j], acc[i][j], 0, 0, 0);
        // counted drain: ensure tile t+1 resident; never vmcnt(0) in steady state
        if (t < 29)      { asm volatile("s_waitcnt vmcnt(8)" ::: "memory"); }
        else if (t == 29){ asm volatile("s_waitcnt vmcnt(4)" ::: "memory"); }
        else             { asm volatile("s_waitcnt vmcnt(0)" ::: "memory"); }
        __builtin_amdgcn_s_barrier();
        cur = (cur == 2) ? 0 : cur + 1;
    }

    // epilogue: C/D layout col=lane&15, row=(lane>>4)*4+e
    const int crowb = row0 + wr + kblk * 4;
    const int ccolb = col0 + wc + laneRow;
    const float* bias = (MODE == 1) ? b0 : (p == 0) ? b0 : (p == 1) ? b1 : (p == 2) ? b2 : b3;
    float bv[4];
    #pragma unroll
    for (int j = 0; j < 4; ++j) bv[j] = bias[ccolb + j * 16];
    #pragma unroll
    for (int i = 0; i < 4; ++i)
        #pragma unroll
        for (int j = 0; j < 4; ++j)
            #pragma unroll
            for (int e = 0; e < 4; ++e) {
                const float val = acc[i][j][e] + bv[j];
                const size_t idx = (size_t)(crowb + i * 16 + e) * 1024 + ccolb + j * 16;
                if (MODE == 1) {
                    Cout[idx] = val;
                } else if (p == 0) {
                    Qo[idx]  = (bf16_t)val;
                    q2o[idx] = (bf16_t)((val >= 0.f ? 0.02f * val : val) * 0.125f);
                } else if (p == 1) {
                    Ko[idx] = (bf16_t)val;
                } else if (p == 2) {
                    Vo[idx] = (bf16_t)val;
                } else {
                    k2o[idx] = (bf16_t)(1.f / (1.f + __expf(-val * 0.000625f)));
                }
            }
}

// ---------------- prep: 5x W transpose-cast (z<5) + x cast (z==5) ----------------
__global__ __launch_bounds__(256) void prep_kernel(
    const float* __restrict__ x, bf16_t* __restrict__ xb,
    const float* __restrict__ W0, const float* __restrict__ W1,
    const float* __restrict__ W2, const float* __restrict__ W3,
    const float* __restrict__ W4, bf16_t* __restrict__ Wt)
{
    const int z = blockIdx.z;
    const int tid = threadIdx.x;
    if (z == 5) {
        const int lin = blockIdx.y * 16 + blockIdx.x;   // 0..255
        #pragma unroll
        for (int u = 0; u < 8; ++u) {
            const size_t s = (size_t)lin * 2048 + u * 256 + tid;
            float4 v = *reinterpret_cast<const float4*>(&x[s * 4]);
            bf16x4 o;
            o[0] = (bf16_t)v.x; o[1] = (bf16_t)v.y; o[2] = (bf16_t)v.z; o[3] = (bf16_t)v.w;
            *reinterpret_cast<bf16x4*>(&xb[s * 4]) = o;
        }
        return;
    }
    const float* W = (z == 0) ? W0 : (z == 1) ? W1 : (z == 2) ? W2 : (z == 3) ? W3 : W4;
    bf16_t* T = Wt + (size_t)z * 1048576;

    __shared__ float Ls[64][65];
    const int k0 = blockIdx.x * 64;
    const int n0 = blockIdx.y * 64;
    const int r  = tid >> 4;
    const int c4 = (tid & 15) * 4;
    #pragma unroll
    for (int i = 0; i < 4; ++i) {
        float4 v = *reinterpret_cast<const float4*>(&W[(size_t)(k0 + r + i * 16) * Dsz + n0 + c4]);
        Ls[r + i * 16][c4 + 0] = v.x;
        Ls[r + i * 16][c4 + 1] = v.y;
        Ls[r + i * 16][c4 + 2] = v.z;
        Ls[r + i * 16][c4 + 3] = v.w;
    }
    __syncthreads();
    #pragma unroll
    for (int i = 0; i < 4; ++i) {
        const int n = r + i * 16;
        bf16x4 o;
        o[0] = (bf16_t)Ls[c4 + 0][n];
        o[1] = (bf16_t)Ls[c4 + 1][n];
        o[2] = (bf16_t)Ls[c4 + 2][n];
        o[3] = (bf16_t)Ls[c4 + 3][n];
        *reinterpret_cast<bf16x4*>(&T[(size_t)(n0 + n) * Dsz + k0 + c4]) = o;
    }
}

// ---------------- MFMA chunk intra: P=A.K^T (causal), dT^T=V^T.K, Oi=P.V ----------------
// A,Kp,Vp: bf16 (B,L,D). Oi: f32 (B,L,D). dT: bf16 [bh][c][e][d] (TRANSPOSED state).
__global__ __launch_bounds__(256) void chunk_intra_kernel(
    const bf16_t* __restrict__ Ap, const bf16_t* __restrict__ Kp,
    const bf16_t* __restrict__ Vp, float* __restrict__ Oi, bf16_t* __restrict__ dT)
{
    __shared__ __align__(16) bf16_t sQ[64 * LPAD];
    __shared__ __align__(16) bf16_t sK[64 * LPAD];
    __shared__ __align__(16) bf16_t sKt[64 * LPAD];
    __shared__ __align__(16) bf16_t sVt[64 * LPAD];
    __shared__ __align__(16) bf16_t sP[64 * LPAD];

    const int bid = blockIdx.x;
    const int c  = bid & (NC - 1);
    const int bh = bid >> 4;
    const int b = bh >> 4, h = bh & 15;
    const int tid = threadIdx.x;
    const size_t gbase = ((size_t)b * Lsz + (size_t)c * 64) * Dsz + h * Dh;

    // stage: Q,K row-major; Kt,Vt transposed
    #pragma unroll
    for (int cc = tid; cc < 512; cc += 256) {
        const int j = cc >> 3;
        const int d0 = (cc & 7) * 8;
        const size_t g = gbase + (size_t)j * 1024 + d0;
        bf16x8 qv = *reinterpret_cast<const bf16x8*>(&Ap[g]);
        bf16x8 kv = *reinterpret_cast<const bf16x8*>(&Kp[g]);
        bf16x8 vv = *reinterpret_cast<const bf16x8*>(&Vp[g]);
        *reinterpret_cast<bf16x8*>(&sQ[j * LPAD + d0]) = qv;
        *reinterpret_cast<bf16x8*>(&sK[j * LPAD + d0]) = kv;
        #pragma unroll
        for (int i = 0; i < 8; ++i) {
            sKt[(d0 + i) * LPAD + j] = kv[i];
            sVt[(d0 + i) * LPAD + j] = vv[i];
        }
    }
    __syncthreads();

    const int w = tid >> 6;
    const int lane = tid & 63;
    const int lr = lane & 15;
    const int kb = lane >> 4;
    const int m0 = w * 16;

    // P = Q.K^T (causal j<=i)
    f32x4v accp[4];
    #pragma unroll
    for (int n = 0; n < 4; ++n) accp[n] = (f32x4v){0.f, 0.f, 0.f, 0.f};
    #pragma unroll
    for (int kk = 0; kk < 2; ++kk) {
        bf16x8 a = *reinterpret_cast<const bf16x8*>(&sQ[(m0 + lr) * LPAD + kk * 32 + kb * 8]);
        #pragma unroll
        for (int n = 0; n < 4; ++n) {
            bf16x8 bb = *reinterpret_cast<const bf16x8*>(&sK[(n * 16 + lr) * LPAD + kk * 32 + kb * 8]);
            accp[n] = __builtin_amdgcn_mfma_f32_16x16x32_bf16(a, bb, accp[n], 0, 0, 0);
        }
    }
    // dT[e][d] = sum_j V[j][e] K[j][d]
    f32x4v acct[4];
    #pragma unroll
    for (int n = 0; n < 4; ++n) acct[n] = (f32x4v){0.f, 0.f, 0.f, 0.f};
    #pragma unroll
    for (int kk = 0; kk < 2; ++kk) {
        bf16x8 a = *reinterpret_cast<const bf16x8*>(&sVt[(m0 + lr) * LPAD + kk * 32 + kb * 8]);
        #pragma unroll
        for (int n = 0; n < 4; ++n) {
            bf16x8 bb = *reinterpret_cast<const bf16x8*>(&sKt[(n * 16 + lr) * LPAD + kk * 32 + kb * 8]);
            acct[n] = __builtin_amdgcn_mfma_f32_16x16x32_bf16(a, bb, acct[n], 0, 0, 0);
        }
    }

    const size_t tbase = (size_t)bid * 4096;
    #pragma unroll
    for (int n = 0; n < 4; ++n)
        #pragma unroll
        for (int e = 0; e < 4; ++e) {
            const int r = m0 + kb * 4 + e;
            const int col = n * 16 + lr;
            dT[tbase + (size_t)r * 64 + col] = (bf16_t)acct[n][e];
            float pv = (col <= r) ? accp[n][e] : 0.f;
            sP[r * LPAD + col] = (bf16_t)pv;
        }
    __syncthreads();

    // Oi = P.V
    f32x4v acco[4];
    #pragma unroll
    for (int n = 0; n < 4; ++n) acco[n] = (f32x4v){0.f, 0.f, 0.f, 0.f};
    #pragma unroll
    for (int kk = 0; kk < 2; ++kk) {
        bf16x8 a = *reinterpret_cast<const bf16x8*>(&sP[(m0 + lr) * LPAD + kk * 32 + kb * 8]);
        #pragma unroll
        for (int n = 0; n < 4; ++n) {
            bf16x8 bb = *reinterpret_cast<const bf16x8*>(&sVt[(n * 16 + lr) * LPAD + kk * 32 + kb * 8]);
            acco[n] = __builtin_amdgcn_mfma_f32_16x16x32_bf16(a, bb, acco[n], 0, 0, 0);
        }
    }
    #pragma unroll
    for (int n = 0; n < 4; ++n)
        #pragma unroll
        for (int e = 0; e < 4; ++e)
            Oi[gbase + (size_t)(m0 + kb * 4 + e) * 1024 + n * 16 + lr] = acco[n][e];
}

// in-place exclusive prefix over chunks (bf16 storage, f32 accumulate)
__global__ __launch_bounds__(256) void chunk_prefix_kernel(bf16_t* dT)
{
    const int g = blockIdx.x;
    const int bh = g >> 4;
    const int slice = g & 15;
    bf16_t* base = dT + (size_t)bh * NC * 4096 + slice * 256 + threadIdx.x;
    float acc = 0.f;
    #pragma unroll
    for (int c = 0; c < NC; ++c) {
        float v = (float)base[(size_t)c * 4096];
        base[(size_t)c * 4096] = (bf16_t)acc;
        acc += v;
    }
}

// ---------------- MFMA chunk inter + fused epilogues ----------------
// O[i][e] = Oi[i][e] + sum_d A[i][d] * S[d][e], with T=S^T stored bf16 [e][d].
// BR1: O1out=O (f32); ebout E[l] = x[l+1]-O1[l] (bf16, l==1023 -> 0); xin = x
// BR2: ebout yb: yb[l+1] = bf16(O1[l+1] + O2[l]); yb[0] = bf16(O1[0]); xin = O1
template<int BR>
__global__ __launch_bounds__(256) void chunk_inter_kernel(
    const bf16_t* __restrict__ Ap, const bf16_t* __restrict__ T,
    const float* __restrict__ Oi, const float* __restrict__ xin,
    float* __restrict__ O1out, bf16_t* __restrict__ ebout)
{
    __shared__ __align__(16) bf16_t sA[64 * LPAD];
    __shared__ __align__(16) bf16_t sT[64 * LPAD];

    const int bid = blockIdx.x;
    const int c  = bid & (NC - 1);
    const int bh = bid >> 4;
    const int b = bh >> 4, h = bh & 15;
    const int tid = threadIdx.x;
    const size_t gbase = ((size_t)b * Lsz + (size_t)c * 64) * Dsz + h * Dh;

    #pragma unroll
    for (int cc = tid; cc < 512; cc += 256) {
        const int j = cc >> 3;
        const int d0 = (cc & 7) * 8;
        bf16x8 av = *reinterpret_cast<const bf16x8*>(&Ap[gbase + (size_t)j * 1024 + d0]);
        *reinterpret_cast<bf16x8*>(&sA[j * LPAD + d0]) = av;
    }
    {
        const size_t tb = (size_t)bid * 4096;
        const int row = tid >> 2;
        const int c16 = (tid & 3) * 16;
        bf16x8 v0 = *reinterpret_cast<const bf16x8*>(&T[tb + (size_t)row * 64 + c16]);
        bf16x8 v1 = *reinterpret_cast<const bf16x8*>(&T[tb + (size_t)row * 64 + c16 + 8]);
        *reinterpret_cast<bf16x8*>(&sT[row * LPAD + c16]) = v0;
        *reinterpret_cast<bf16x8*>(&sT[row * LPAD + c16 + 8]) = v1;
    }
    __syncthreads();

    const int w = tid >> 6;
    const int lane = tid & 63;
    const int lr = lane & 15;
    const int kb = lane >> 4;
    const int m0 = w * 16;

    f32x4v acc[4];
    #pragma unroll
    for (int n = 0; n < 4; ++n) acc[n] = (f32x4v){0.f, 0.f, 0.f, 0.f};
    #pragma unroll
    for (int kk = 0; kk < 2; ++kk) {
        bf16x8 a = *reinterpret_cast<const bf16x8*>(&sA[(m0 + lr) * LPAD + kk * 32 + kb * 8]);
        #pragma unroll
        for (int n = 0; n < 4; ++n) {
            bf16x8 bb = *reinterpret_cast<const bf16x8*>(&sT[(n * 16 + lr) * LPAD + kk * 32 + kb * 8]);
            acc[n] = __builtin_amdgcn_mfma_f32_16x16x32_bf16(a, bb, acc[n], 0, 0, 0);
        }
    }

    #pragma unroll
    for (int n = 0; n < 4; ++n)
        #pragma unroll
        for (int e = 0; e < 4; ++e) {
            const int iLoc = m0 + kb * 4 + e;
            const int lglob = c * 64 + iLoc;
            const size_t idx = gbase + (size_t)iLoc * 1024 + n * 16 + lr;
            const float val = acc[n][e] + Oi[idx];
            if (BR == 1) {
                O1out[idx] = val;
                float ev = 0.f;
                if (lglob < Lsz - 1) ev = xin[idx + 1024] - val;
                ebout[idx] = (bf16_t)ev;
            } else {
                if (lglob < Lsz - 1) ebout[idx + 1024] = (bf16_t)(xin[idx + 1024] + val);
                if (lglob == 0)      ebout[idx] = (bf16_t)(xin[idx]);
            }
        }
}

extern "C" void kernel_launch(void* const* d_in, const int* in_sizes, int n_in,
                              void* d_out, int out_size, void* d_ws, size_t ws_size,
                              hipStream_t stream) {
    const float* x   = (const float*)d_in[0];
    const float* Wq  = (const float*)d_in[1];
    const float* bq  = (const float*)d_in[2];
    const float* Wk1 = (const float*)d_in[3];
    const float* bk1 = (const float*)d_in[4];
    const float* Wv  = (const float*)d_in[5];
    const float* bv  = (const float*)d_in[6];
    const float* Wk2 = (const float*)d_in[7];
    const float* bk2 = (const float*)d_in[8];
    const float* Wp  = (const float*)d_in[9];
    const float* bp  = (const float*)d_in[10];
    float* out = (float*)d_out;
    float* ws  = (float*)d_ws;

    const size_t mat = (size_t)Mtot * Dsz;   // 2M elements
    float*  O1  = ws;                          // f32 (B,L,D)
    float*  Oib = ws + mat;                    // f32 intra out
    bf16_t* dT  = (bf16_t*)(ws + 2 * mat);     // bf16 states [bh][c][4096] (1M f32 slots)
    bf16_t* xb  = (bf16_t*)(ws + 2 * mat + mat / 2);
    bf16_t* Wt  = (bf16_t*)(ws + 3 * mat);     // 5 x 1M bf16 = 2.5M f32
    float*  b16base = ws + 3 * mat + 3 * mat;  // ws + 6M (slack after Wt's 2.5M)
    bf16_t* Qr  = (bf16_t*)(b16base);
    bf16_t* q2  = (bf16_t*)(b16base + mat / 2);
    bf16_t* Kb  = (bf16_t*)(b16base + 2 * (mat / 2));
    bf16_t* Vb  = (bf16_t*)(b16base + 3 * (mat / 2));
    bf16_t* k2  = (bf16_t*)(b16base + 4 * (mat / 2));
    bf16_t* Eb  = (bf16_t*)(b16base + 5 * (mat / 2));
    bf16_t* yb  = (bf16_t*)(b16base + 6 * (mat / 2));

    dim3 block(256);

    prep_kernel<<<dim3(16, 16, 6), block, 0, stream>>>(x, xb, Wq, Wk1, Wv, Wk2, Wp, Wt);

    // fused Q/K/V/Z projections with elementwise epilogues (512 blocks, XCD-mapped)
    bgemm_kernel<0><<<dim3(512), block, 0, stream>>>(
        xb, Wt, bq, bk1, bv, bk2, Qr, q2, Kb, Vb, k2, nullptr);

    // branch 1
    chunk_intra_kernel<<<dim3(512), block, 0, stream>>>(Qr, Kb, Vb, Oib, dT);
    chunk_prefix_kernel<<<dim3(512), block, 0, stream>>>(dT);
    chunk_inter_kernel<1><<<dim3(512), block, 0, stream>>>(Qr, dT, Oib, x, O1, Eb);
    // branch 2
    chunk_intra_kernel<<<dim3(512), block, 0, stream>>>(q2, k2, Eb, Oib, dT);
    chunk_prefix_kernel<<<dim3(512), block, 0, stream>>>(dT);
    chunk_inter_kernel<2><<<dim3(512), block, 0, stream>>>(q2, dT, Oib, O1, nullptr, yb);

    bgemm_kernel<1><<<dim3(128), block, 0, stream>>>(
        yb, Wt + 4 * 1048576, bp, nullptr, nullptr, nullptr,
        nullptr, nullptr, nullptr, nullptr, nullptr, out);
}

// Round 9
// 100.711 us; speedup vs baseline: 1.2989x; 1.0097x over previous
//
#include <hip/hip_runtime.h>
#include <hip/hip_bf16.h>
#include <math.h>

#define Bsz 2
#define Lsz 1024
#define Dsz 1024
#define Hsz 16
#define Dh 64
#define Mtot (Bsz*Lsz)   // 2048
#define NC (Lsz/64)      // 16 chunks per (b,h)
#define LPAD 72          // LDS row pitch (bf16): 144B = 9*16B

typedef __bf16 bf16_t;
typedef bf16_t bf16x8 __attribute__((ext_vector_type(8)));
typedef bf16_t bf16x4 __attribute__((ext_vector_type(4)));
typedef float f32x4v __attribute__((ext_vector_type(4)));

__device__ __forceinline__ void gload16(const void* g, void* l) {
    __builtin_amdgcn_global_load_lds(
        (const __attribute__((address_space(1))) unsigned int*)g,
        (__attribute__((address_space(3))) unsigned int*)l, 16, 0, 0);
}

// ---------------- bf16 MFMA GEMM, 4-buffer 3-ahead pipeline ----------------
// One barrier per K-step: tile t+3 stages into buf[(t+3)&3] = buf[(t-1)&3],
// whose reads completed before the end-of-step-(t-1) barrier (MFMA operand
// dependency forces lgkm drain pre-barrier). LDS 64KB -> 2 blocks/CU.
// MODE 0: A(2048x1024) @ Wt[0..3]^T fused (512 blocks); epilogue writes bf16
//         Q, q2=f(Q), K, V, k2=sigmoid(z*0.02/32). MODE 1: final GEMM, f32 out.
// XCD-aware mapping: blockIdx.x%8 = XCD; each XCD owns a square block region.
template<int MODE>
__global__ __launch_bounds__(256) void bgemm_kernel(
    const bf16_t* __restrict__ A, const bf16_t* __restrict__ Bt,
    const float* b0, const float* b1, const float* b2, const float* b3,
    bf16_t* Qo, bf16_t* q2o, bf16_t* Ko, bf16_t* Vo, bf16_t* k2o, float* Cout)
{
    __shared__ __align__(16) bf16_t As[4][4096];
    __shared__ __align__(16) bf16_t Bs[4][4096];
    const int tid  = threadIdx.x;
    const int lane = tid & 63;
    const int wid  = tid >> 6;

    const int lin = blockIdx.x;
    const int xcd = lin & 7;
    const int t0  = lin >> 3;
    int brow, bcolg;
    if (MODE == 0) {            // 2x4 regions of 8x8 blocks (16 rows x 32 cols)
        brow  = (xcd & 1) * 8 + (t0 & 7);
        bcolg = (xcd >> 1) * 8 + (t0 >> 3);
    } else {                    // 4x2 regions of 4x4 blocks (16 rows x 8 cols)
        brow  = (xcd & 3) * 4 + (t0 & 3);
        bcolg = (xcd >> 2) * 4 + (t0 >> 2);
    }
    const int row0  = brow * 128;
    const int col0g = bcolg * 128;
    const int p    = col0g >> 10;
    const int col0 = col0g & 1023;
    const int wr = (wid >> 1) * 64;
    const int wc = (wid & 1) * 64;

    const int srow = tid >> 2;
    const int scol = tid & 3;
    const int ssw  = (srow & 3) ^ ((srow >> 2) & 3);
    const int scol_sw = scol ^ ssw;
    const bf16_t* gA0 = A  + (size_t)(row0 + srow)       * 1024 + scol_sw * 8;
    const bf16_t* gA1 = A  + (size_t)(row0 + srow + 64)  * 1024 + scol_sw * 8;
    const bf16_t* gB0 = Bt + (size_t)(col0g + srow)      * 1024 + scol_sw * 8;
    const bf16_t* gB1 = Bt + (size_t)(col0g + srow + 64) * 1024 + scol_sw * 8;

    const int laneRow = lane & 15;
    const int kblk = lane >> 4;
    const int swz = (kblk ^ (laneRow & 3) ^ ((laneRow >> 2) & 3)) & 3;
    const int aoff = (wr + laneRow) * 32 + swz * 8;
    const int boff = (wc + laneRow) * 32 + swz * 8;

    f32x4v acc[4][4];
    #pragma unroll
    for (int i = 0; i < 4; ++i)
        #pragma unroll
        for (int j = 0; j < 4; ++j)
            acc[i][j] = (f32x4v){0.f, 0.f, 0.f, 0.f};

    auto stage = [&](int buf) {
        gload16(gA0, &As[buf][tid * 8]);
        gload16(gA1, &As[buf][(tid + 256) * 8]);
        gload16(gB0, &Bs[buf][tid * 8]);
        gload16(gB1, &Bs[buf][(tid + 256) * 8]);
        gA0 += 32; gA1 += 32; gB0 += 32; gB1 += 32;
    };

    stage(0); stage(1); stage(2);                      // 12 loads in flight
    asm volatile("s_waitcnt vmcnt(8)" ::: "memory");   // tile 0 resident
    __builtin_amdgcn_s_barrier();

    for (int t = 0; t < 32; ++t) {
        const int cur = t & 3;
        bf16x8 af[4], bfr[4];
        #pragma unroll
        for (int f = 0; f < 4; ++f) {
            af[f]  = *reinterpret_cast<const bf16x8*>(&As[cur][aoff + f * 512]);
            bfr[f] = *reinterpret_cast<const bf16x8*>(&Bs[cur][boff + f * 512]);
        }
        if (t < 29) stage((t + 3) & 3);     // buffer last read at t-1: fenced
        #pragma unroll
        for (int i = 0; i < 4; ++i)
            #pragma unroll
            for (int j = 0; j < 4; ++j)
                acc[i][j] = __builtin_amdgcn_mfma_f32_16x16x32_bf16(af[i], bfr[j], acc[i][j], 0, 0, 0);
        // counted drain: next tile resident before crossing the barrier
        if (t < 29)      { asm volatile("s_waitcnt vmcnt(8)" ::: "memory"); }
        else if (t == 29){ asm volatile("s_waitcnt vmcnt(4)" ::: "memory"); }
        else if (t == 30){ asm volatile("s_waitcnt vmcnt(0)" ::: "memory"); }
        if (t < 31) __builtin_amdgcn_s_barrier();
    }

    // epilogue: C/D layout col=lane&15, row=(lane>>4)*4+e
    const int crowb = row0 + wr + kblk * 4;
    const int ccolb = col0 + wc + laneRow;
    const float* bias = (MODE == 1) ? b0 : (p == 0) ? b0 : (p == 1) ? b1 : (p == 2) ? b2 : b3;
    float bv[4];
    #pragma unroll
    for (int j = 0; j < 4; ++j) bv[j] = bias[ccolb + j * 16];
    #pragma unroll
    for (int i = 0; i < 4; ++i)
        #pragma unroll
        for (int j = 0; j < 4; ++j)
            #pragma unroll
            for (int e = 0; e < 4; ++e) {
                const float val = acc[i][j][e] + bv[j];
                const size_t idx = (size_t)(crowb + i * 16 + e) * 1024 + ccolb + j * 16;
                if (MODE == 1) {
                    Cout[idx] = val;
                } else if (p == 0) {
                    Qo[idx]  = (bf16_t)val;
                    q2o[idx] = (bf16_t)((val >= 0.f ? 0.02f * val : val) * 0.125f);
                } else if (p == 1) {
                    Ko[idx] = (bf16_t)val;
                } else if (p == 2) {
                    Vo[idx] = (bf16_t)val;
                } else {
                    k2o[idx] = (bf16_t)(1.f / (1.f + __expf(-val * 0.000625f)));
                }
            }
}

// ---------------- prep: 5x W transpose-cast (z<5) + x cast (z==5) ----------------
__global__ __launch_bounds__(256) void prep_kernel(
    const float* __restrict__ x, bf16_t* __restrict__ xb,
    const float* __restrict__ W0, const float* __restrict__ W1,
    const float* __restrict__ W2, const float* __restrict__ W3,
    const float* __restrict__ W4, bf16_t* __restrict__ Wt)
{
    const int z = blockIdx.z;
    const int tid = threadIdx.x;
    if (z == 5) {
        const int lin = blockIdx.y * 16 + blockIdx.x;   // 0..255
        #pragma unroll
        for (int u = 0; u < 8; ++u) {
            const size_t s = (size_t)lin * 2048 + u * 256 + tid;
            float4 v = *reinterpret_cast<const float4*>(&x[s * 4]);
            bf16x4 o;
            o[0] = (bf16_t)v.x; o[1] = (bf16_t)v.y; o[2] = (bf16_t)v.z; o[3] = (bf16_t)v.w;
            *reinterpret_cast<bf16x4*>(&xb[s * 4]) = o;
        }
        return;
    }
    const float* W = (z == 0) ? W0 : (z == 1) ? W1 : (z == 2) ? W2 : (z == 3) ? W3 : W4;
    bf16_t* T = Wt + (size_t)z * 1048576;

    __shared__ float Ls[64][65];
    const int k0 = blockIdx.x * 64;
    const int n0 = blockIdx.y * 64;
    const int r  = tid >> 4;
    const int c4 = (tid & 15) * 4;
    #pragma unroll
    for (int i = 0; i < 4; ++i) {
        float4 v = *reinterpret_cast<const float4*>(&W[(size_t)(k0 + r + i * 16) * Dsz + n0 + c4]);
        Ls[r + i * 16][c4 + 0] = v.x;
        Ls[r + i * 16][c4 + 1] = v.y;
        Ls[r + i * 16][c4 + 2] = v.z;
        Ls[r + i * 16][c4 + 3] = v.w;
    }
    __syncthreads();
    #pragma unroll
    for (int i = 0; i < 4; ++i) {
        const int n = r + i * 16;
        bf16x4 o;
        o[0] = (bf16_t)Ls[c4 + 0][n];
        o[1] = (bf16_t)Ls[c4 + 1][n];
        o[2] = (bf16_t)Ls[c4 + 2][n];
        o[3] = (bf16_t)Ls[c4 + 3][n];
        *reinterpret_cast<bf16x4*>(&T[(size_t)(n0 + n) * Dsz + k0 + c4]) = o;
    }
}

// ---------------- MFMA chunk intra: P=A.K^T (causal), dT^T=V^T.K, Oi=P.V ----------------
// A,Kp,Vp: bf16 (B,L,D). Oi: bf16 (B,L,D). dT: bf16 [bh][c][e][d] (transposed state).
__global__ __launch_bounds__(256) void chunk_intra_kernel(
    const bf16_t* __restrict__ Ap, const bf16_t* __restrict__ Kp,
    const bf16_t* __restrict__ Vp, bf16_t* __restrict__ Oi, bf16_t* __restrict__ dT)
{
    __shared__ __align__(16) bf16_t sQ[64 * LPAD];
    __shared__ __align__(16) bf16_t sK[64 * LPAD];
    __shared__ __align__(16) bf16_t sKt[64 * LPAD];
    __shared__ __align__(16) bf16_t sVt[64 * LPAD];
    __shared__ __align__(16) bf16_t sP[64 * LPAD];

    const int bid = blockIdx.x;
    const int c  = bid & (NC - 1);
    const int bh = bid >> 4;
    const int b = bh >> 4, h = bh & 15;
    const int tid = threadIdx.x;
    const size_t gbase = ((size_t)b * Lsz + (size_t)c * 64) * Dsz + h * Dh;

    #pragma unroll
    for (int cc = tid; cc < 512; cc += 256) {
        const int j = cc >> 3;
        const int d0 = (cc & 7) * 8;
        const size_t g = gbase + (size_t)j * 1024 + d0;
        bf16x8 qv = *reinterpret_cast<const bf16x8*>(&Ap[g]);
        bf16x8 kv = *reinterpret_cast<const bf16x8*>(&Kp[g]);
        bf16x8 vv = *reinterpret_cast<const bf16x8*>(&Vp[g]);
        *reinterpret_cast<bf16x8*>(&sQ[j * LPAD + d0]) = qv;
        *reinterpret_cast<bf16x8*>(&sK[j * LPAD + d0]) = kv;
        #pragma unroll
        for (int i = 0; i < 8; ++i) {
            sKt[(d0 + i) * LPAD + j] = kv[i];
            sVt[(d0 + i) * LPAD + j] = vv[i];
        }
    }
    __syncthreads();

    const int w = tid >> 6;
    const int lane = tid & 63;
    const int lr = lane & 15;
    const int kb = lane >> 4;
    const int m0 = w * 16;

    f32x4v accp[4];
    #pragma unroll
    for (int n = 0; n < 4; ++n) accp[n] = (f32x4v){0.f, 0.f, 0.f, 0.f};
    #pragma unroll
    for (int kk = 0; kk < 2; ++kk) {
        bf16x8 a = *reinterpret_cast<const bf16x8*>(&sQ[(m0 + lr) * LPAD + kk * 32 + kb * 8]);
        #pragma unroll
        for (int n = 0; n < 4; ++n) {
            bf16x8 bb = *reinterpret_cast<const bf16x8*>(&sK[(n * 16 + lr) * LPAD + kk * 32 + kb * 8]);
            accp[n] = __builtin_amdgcn_mfma_f32_16x16x32_bf16(a, bb, accp[n], 0, 0, 0);
        }
    }
    f32x4v acct[4];
    #pragma unroll
    for (int n = 0; n < 4; ++n) acct[n] = (f32x4v){0.f, 0.f, 0.f, 0.f};
    #pragma unroll
    for (int kk = 0; kk < 2; ++kk) {
        bf16x8 a = *reinterpret_cast<const bf16x8*>(&sVt[(m0 + lr) * LPAD + kk * 32 + kb * 8]);
        #pragma unroll
        for (int n = 0; n < 4; ++n) {
            bf16x8 bb = *reinterpret_cast<const bf16x8*>(&sKt[(n * 16 + lr) * LPAD + kk * 32 + kb * 8]);
            acct[n] = __builtin_amdgcn_mfma_f32_16x16x32_bf16(a, bb, acct[n], 0, 0, 0);
        }
    }

    const size_t tbase = (size_t)bid * 4096;
    #pragma unroll
    for (int n = 0; n < 4; ++n)
        #pragma unroll
        for (int e = 0; e < 4; ++e) {
            const int r = m0 + kb * 4 + e;
            const int col = n * 16 + lr;
            dT[tbase + (size_t)r * 64 + col] = (bf16_t)acct[n][e];
            float pv = (col <= r) ? accp[n][e] : 0.f;
            sP[r * LPAD + col] = (bf16_t)pv;
        }
    __syncthreads();

    f32x4v acco[4];
    #pragma unroll
    for (int n = 0; n < 4; ++n) acco[n] = (f32x4v){0.f, 0.f, 0.f, 0.f};
    #pragma unroll
    for (int kk = 0; kk < 2; ++kk) {
        bf16x8 a = *reinterpret_cast<const bf16x8*>(&sP[(m0 + lr) * LPAD + kk * 32 + kb * 8]);
        #pragma unroll
        for (int n = 0; n < 4; ++n) {
            bf16x8 bb = *reinterpret_cast<const bf16x8*>(&sVt[(n * 16 + lr) * LPAD + kk * 32 + kb * 8]);
            acco[n] = __builtin_amdgcn_mfma_f32_16x16x32_bf16(a, bb, acco[n], 0, 0, 0);
        }
    }
    #pragma unroll
    for (int n = 0; n < 4; ++n)
        #pragma unroll
        for (int e = 0; e < 4; ++e)
            Oi[gbase + (size_t)(m0 + kb * 4 + e) * 1024 + n * 16 + lr] = (bf16_t)acco[n][e];
}

// ---------------- MFMA chunk inter, on-the-fly dT prefix + fused epilogues ----------------
// S^T(chunk c) = sum_{c'<c} dT[bh][c'] computed in-kernel (dT L2-resident).
// O[i][e] = Oi[i][e] + sum_d A[i][d] * S[d][e].
// BR1: O1out=O (f32); ebout E[l] = x[l+1]-O1[l] (bf16, l==1023 -> 0); xin = f32 x
// BR2: ebout yb: yb[l+1] = bf16(o1in[l+1] + O2[l]); yb[0] = bf16(o1in[0])
template<int BR>
__global__ __launch_bounds__(256) void chunk_inter_kernel(
    const bf16_t* __restrict__ Ap, const bf16_t* __restrict__ dT,
    const bf16_t* __restrict__ Oi, const float* __restrict__ xin,
    const float* __restrict__ o1in, float* __restrict__ O1out,
    bf16_t* __restrict__ ebout)
{
    __shared__ __align__(16) bf16_t sA[64 * LPAD];
    __shared__ __align__(16) bf16_t sT[64 * LPAD];

    const int bid = blockIdx.x;
    const int c  = bid & (NC - 1);
    const int bh = bid >> 4;
    const int b = bh >> 4, h = bh & 15;
    const int tid = threadIdx.x;
    const size_t gbase = ((size_t)b * Lsz + (size_t)c * 64) * Dsz + h * Dh;

    #pragma unroll
    for (int cc = tid; cc < 512; cc += 256) {
        const int j = cc >> 3;
        const int d0 = (cc & 7) * 8;
        bf16x8 av = *reinterpret_cast<const bf16x8*>(&Ap[gbase + (size_t)j * 1024 + d0]);
        *reinterpret_cast<bf16x8*>(&sA[j * LPAD + d0]) = av;
    }
    {
        // exclusive prefix over chunks, f32 accumulate; 16 elems per thread
        const bf16_t* tb = dT + (size_t)bh * NC * 4096 + tid * 16;
        float acc[16];
        #pragma unroll
        for (int k = 0; k < 16; ++k) acc[k] = 0.f;
        for (int cc = 0; cc < c; ++cc) {
            bf16x8 v0 = *reinterpret_cast<const bf16x8*>(&tb[(size_t)cc * 4096]);
            bf16x8 v1 = *reinterpret_cast<const bf16x8*>(&tb[(size_t)cc * 4096 + 8]);
            #pragma unroll
            for (int k = 0; k < 8; ++k) { acc[k] += (float)v0[k]; acc[8 + k] += (float)v1[k]; }
        }
        const int row = tid >> 2;
        const int c16 = (tid & 3) * 16;
        bf16x8 o0, o1v;
        #pragma unroll
        for (int k = 0; k < 8; ++k) { o0[k] = (bf16_t)acc[k]; o1v[k] = (bf16_t)acc[8 + k]; }
        *reinterpret_cast<bf16x8*>(&sT[row * LPAD + c16]) = o0;
        *reinterpret_cast<bf16x8*>(&sT[row * LPAD + c16 + 8]) = o1v;
    }
    __syncthreads();

    const int w = tid >> 6;
    const int lane = tid & 63;
    const int lr = lane & 15;
    const int kb = lane >> 4;
    const int m0 = w * 16;

    f32x4v acc[4];
    #pragma unroll
    for (int n = 0; n < 4; ++n) acc[n] = (f32x4v){0.f, 0.f, 0.f, 0.f};
    #pragma unroll
    for (int kk = 0; kk < 2; ++kk) {
        bf16x8 a = *reinterpret_cast<const bf16x8*>(&sA[(m0 + lr) * LPAD + kk * 32 + kb * 8]);
        #pragma unroll
        for (int n = 0; n < 4; ++n) {
            bf16x8 bb = *reinterpret_cast<const bf16x8*>(&sT[(n * 16 + lr) * LPAD + kk * 32 + kb * 8]);
            acc[n] = __builtin_amdgcn_mfma_f32_16x16x32_bf16(a, bb, acc[n], 0, 0, 0);
        }
    }

    #pragma unroll
    for (int n = 0; n < 4; ++n)
        #pragma unroll
        for (int e = 0; e < 4; ++e) {
            const int iLoc = m0 + kb * 4 + e;
            const int lglob = c * 64 + iLoc;
            const size_t idx = gbase + (size_t)iLoc * 1024 + n * 16 + lr;
            const float val = acc[n][e] + (float)Oi[idx];
            if (BR == 1) {
                O1out[idx] = val;
                float ev = 0.f;
                if (lglob < Lsz - 1) ev = xin[idx + 1024] - val;
                ebout[idx] = (bf16_t)ev;
            } else {
                if (lglob < Lsz - 1) ebout[idx + 1024] = (bf16_t)(o1in[idx + 1024] + val);
                if (lglob == 0)      ebout[idx] = (bf16_t)(o1in[idx]);
            }
        }
}

extern "C" void kernel_launch(void* const* d_in, const int* in_sizes, int n_in,
                              void* d_out, int out_size, void* d_ws, size_t ws_size,
                              hipStream_t stream) {
    const float* x   = (const float*)d_in[0];
    const float* Wq  = (const float*)d_in[1];
    const float* bq  = (const float*)d_in[2];
    const float* Wk1 = (const float*)d_in[3];
    const float* bk1 = (const float*)d_in[4];
    const float* Wv  = (const float*)d_in[5];
    const float* bv  = (const float*)d_in[6];
    const float* Wk2 = (const float*)d_in[7];
    const float* bk2 = (const float*)d_in[8];
    const float* Wp  = (const float*)d_in[9];
    const float* bp  = (const float*)d_in[10];
    float* out = (float*)d_out;
    float* ws  = (float*)d_ws;

    const size_t mat = (size_t)Mtot * Dsz;     // 2M elements
    float*  O1  = ws;                           // f32, 2M slots      [0, 2M)
    bf16_t* Oib = (bf16_t*)(ws + 2 * mat);      // bf16 2M -> 1M      [2M, 3M)
    bf16_t* dT  = (bf16_t*)(ws + 3 * mat);      // bf16 2M -> 1M      [3M, 4M)
    bf16_t* xb  = (bf16_t*)(ws + 4 * mat);      // bf16 2M -> 1M      [4M, 5M)
    bf16_t* Wt  = (bf16_t*)(ws + 5 * mat);      // bf16 5M -> 2.5M    [5M, 7.5M)
    float*  bb  = ws + 7 * mat + mat / 2;       // 7.5M
    bf16_t* Qr  = (bf16_t*)(bb);                // [7.5M, 8.5M)       (aliased by yb)
    bf16_t* q2  = (bf16_t*)(bb + mat / 2);      // [8.5M, 9.5M)
    bf16_t* Kb  = (bf16_t*)(bb + mat);          // [9.5M, 10.5M)
    bf16_t* Vb  = (bf16_t*)(bb + 3 * mat / 2);  // [10.5M, 11.5M)
    bf16_t* k2  = (bf16_t*)(bb + 2 * mat);      // [11.5M, 12.5M)
    bf16_t* Eb  = (bf16_t*)(bb + 5 * mat / 2);  // [12.5M, 13.5M) own buffer (round-8 alias raced)
    bf16_t* yb  = Qr;                           // Qr dead after inter<1>

    dim3 block(256);

    prep_kernel<<<dim3(16, 16, 6), block, 0, stream>>>(x, xb, Wq, Wk1, Wv, Wk2, Wp, Wt);

    bgemm_kernel<0><<<dim3(512), block, 0, stream>>>(
        xb, Wt, bq, bk1, bv, bk2, Qr, q2, Kb, Vb, k2, nullptr);

    // branch 1
    chunk_intra_kernel<<<dim3(512), block, 0, stream>>>(Qr, Kb, Vb, Oib, dT);
    chunk_inter_kernel<1><<<dim3(512), block, 0, stream>>>(Qr, dT, Oib, x, nullptr, O1, Eb);
    // branch 2
    chunk_intra_kernel<<<dim3(512), block, 0, stream>>>(q2, k2, Eb, Oib, dT);
    chunk_inter_kernel<2><<<dim3(512), block, 0, stream>>>(q2, dT, Oib, nullptr, O1, nullptr, yb);

    bgemm_kernel<1><<<dim3(128), block, 0, stream>>>(
        yb, Wt + 4 * 1048576, bp, nullptr, nullptr, nullptr,
        nullptr, nullptr, nullptr, nullptr, nullptr, out);
}